// Round 1
// baseline (277.132 us; speedup 1.0000x reference)
//
#include <hip/hip_runtime.h>

#define ERROR_OK 0.1f

constexpr int BLOCK = 256;
constexpr int GRID  = 2048;   // 8 blocks/CU worth of work queued across 256 CUs

// Stage 1: grid-stride float4 streaming, per-block partial sums into d_ws.
__global__ __launch_bounds__(BLOCK) void dz_partial_kernel(
    const float4* __restrict__ a,
    const float4* __restrict__ b,
    float* __restrict__ partials,
    int n4)
{
    int tid    = blockIdx.x * BLOCK + threadIdx.x;
    int stride = gridDim.x * BLOCK;

    float sum = 0.0f;
    for (int i = tid; i < n4; i += stride) {
        float4 va = a[i];
        float4 vb = b[i];
        float d0 = va.x - vb.x;
        float d1 = va.y - vb.y;
        float d2 = va.z - vb.z;
        float d3 = va.w - vb.w;
        // dead-zone: zero if |d| < ERROR_OK, else keep; then square
        d0 = (fabsf(d0) < ERROR_OK) ? 0.0f : d0;
        d1 = (fabsf(d1) < ERROR_OK) ? 0.0f : d1;
        d2 = (fabsf(d2) < ERROR_OK) ? 0.0f : d2;
        d3 = (fabsf(d3) < ERROR_OK) ? 0.0f : d3;
        sum += d0 * d0 + d1 * d1 + d2 * d2 + d3 * d3;
    }

    // wave-64 butterfly reduce
    #pragma unroll
    for (int off = 32; off > 0; off >>= 1)
        sum += __shfl_down(sum, off, 64);

    __shared__ float smem[BLOCK / 64];
    int lane = threadIdx.x & 63;
    int wave = threadIdx.x >> 6;
    if (lane == 0) smem[wave] = sum;
    __syncthreads();

    if (threadIdx.x == 0) {
        float s = 0.0f;
        #pragma unroll
        for (int w = 0; w < BLOCK / 64; ++w) s += smem[w];
        partials[blockIdx.x] = s;
    }
}

// Stage 2: single block reduces GRID partials, scales by 1/N. Deterministic
// (no float atomics -> consistent across rocprof replay passes).
__global__ __launch_bounds__(BLOCK) void dz_final_kernel(
    const float* __restrict__ partials,
    float* __restrict__ out,
    int nparts,
    float inv_n)
{
    float sum = 0.0f;
    for (int i = threadIdx.x; i < nparts; i += BLOCK)
        sum += partials[i];

    #pragma unroll
    for (int off = 32; off > 0; off >>= 1)
        sum += __shfl_down(sum, off, 64);

    __shared__ float smem[BLOCK / 64];
    int lane = threadIdx.x & 63;
    int wave = threadIdx.x >> 6;
    if (lane == 0) smem[wave] = sum;
    __syncthreads();

    if (threadIdx.x == 0) {
        float s = 0.0f;
        #pragma unroll
        for (int w = 0; w < BLOCK / 64; ++w) s += smem[w];
        out[0] = s * inv_n;
    }
}

extern "C" void kernel_launch(void* const* d_in, const int* in_sizes, int n_in,
                              void* d_out, int out_size, void* d_ws, size_t ws_size,
                              hipStream_t stream) {
    const float4* a = (const float4*)d_in[0];
    const float4* b = (const float4*)d_in[1];
    float* out      = (float*)d_out;
    float* partials = (float*)d_ws;   // GRID floats = 8 KiB scratch

    const int n  = in_sizes[0];       // 33554432, divisible by 4
    const int n4 = n / 4;

    dz_partial_kernel<<<GRID, BLOCK, 0, stream>>>(a, b, partials, n4);
    dz_final_kernel<<<1, BLOCK, 0, stream>>>(partials, out, GRID, 1.0f / (float)n);
}